// Round 14
// baseline (1392.578 us; speedup 1.0000x reference)
//
#include <hip/hip_runtime.h>
#include <stdint.h>
#include <stddef.h>

#define B_SZ   2
#define N_PTS  15000
#define MPT    1024
#define CSEED  512
#define HMINF (-0.02f)
#define HMAXF (0.06f)

typedef __attribute__((ext_vector_type(8))) short bf16x8;
typedef __attribute__((ext_vector_type(4))) float f32x4;
typedef __attribute__((ext_vector_type(2))) float f32x2;

__device__ inline unsigned short f2bf(float f) {
    unsigned u = __float_as_uint(f);
    unsigned r = (u + 0x7fffu + ((u >> 16) & 1u)) >> 16;   // RNE, finite inputs
    return (unsigned short)r;
}

// ---------------------------------------------------------------- masked FPS v14: packed-fp32 inner loop
// v11 structure (8 waves, 2/SIMD = proven optimum) + the 16-pt distance loop
// rewritten as 8x f32x2 with `#pragma clang fp contract(off)`: maps to
// v_pk_sub/mul/add_f32 (2 fp32 per issue slot), halving the dominant issue
// term (~208 -> ~144 inst core). contract(off) keeps mul/add separate ->
// BIT-IDENTICAL to the scalar __fmul_rn/__fadd_rn sequence (same assoc
// ((dx2+dy2)+dz2)), so selection indices cannot change.
// Blocks >= B_SZ convert W2->bf16 on otherwise-idle CUs, overlapped under FPS.
#define FPS_T     512
#define FPS_CAP   8192          // 16 slots x 512 thr; Mc>CAP -> exact fallback
#define FPS_K     16
#define W2_BLKS   128           // 128 x 512 x 8 = 524288 floats exactly

__device__ inline unsigned dpp_max_u32(unsigned v) {   // valid in lane 63 (fallback)
    unsigned t;
    t = (unsigned)__builtin_amdgcn_update_dpp(0, (int)v, 0x111, 0xf, 0xf, false); v = v > t ? v : t;
    t = (unsigned)__builtin_amdgcn_update_dpp(0, (int)v, 0x112, 0xf, 0xf, false); v = v > t ? v : t;
    t = (unsigned)__builtin_amdgcn_update_dpp(0, (int)v, 0x114, 0xf, 0xf, false); v = v > t ? v : t;
    t = (unsigned)__builtin_amdgcn_update_dpp(0, (int)v, 0x118, 0xf, 0xf, false); v = v > t ? v : t;
    t = (unsigned)__builtin_amdgcn_update_dpp(0, (int)v, 0x142, 0xf, 0xf, false); v = v > t ? v : t;
    t = (unsigned)__builtin_amdgcn_update_dpp(0, (int)v, 0x143, 0xf, 0xf, false); v = v > t ? v : t;
    return v;
}
__device__ inline int dpp_min_i32(int v) {             // valid in lane 63 (fallback)
    int t;
    t = __builtin_amdgcn_update_dpp(0x7fffffff, v, 0x111, 0xf, 0xf, false); v = v < t ? v : t;
    t = __builtin_amdgcn_update_dpp(0x7fffffff, v, 0x112, 0xf, 0xf, false); v = v < t ? v : t;
    t = __builtin_amdgcn_update_dpp(0x7fffffff, v, 0x114, 0xf, 0xf, false); v = v < t ? v : t;
    t = __builtin_amdgcn_update_dpp(0x7fffffff, v, 0x118, 0xf, 0xf, false); v = v < t ? v : t;
    t = __builtin_amdgcn_update_dpp(0x7fffffff, v, 0x142, 0xf, 0xf, false); v = v < t ? v : t;
    t = __builtin_amdgcn_update_dpp(0x7fffffff, v, 0x143, 0xf, 0xf, false); v = v < t ? v : t;
    return v;
}

#define DPP_STEP_MAX64(v, ctrl)                                                              \
    {                                                                                        \
        unsigned _hi = (unsigned)((v) >> 32), _lo = (unsigned)(v);                           \
        unsigned _th = (unsigned)__builtin_amdgcn_update_dpp(0, (int)_hi, ctrl, 0xf, 0xf, false); \
        unsigned _tl = (unsigned)__builtin_amdgcn_update_dpp(0, (int)_lo, ctrl, 0xf, 0xf, false); \
        uint64_t _t = ((uint64_t)_th << 32) | _tl;                                           \
        (v) = _t > (v) ? _t : (v);                                                           \
    }

__device__ inline uint64_t dpp_max64_to63(uint64_t v) {  // valid in lane 63
    DPP_STEP_MAX64(v, 0x111); DPP_STEP_MAX64(v, 0x112); DPP_STEP_MAX64(v, 0x114);
    DPP_STEP_MAX64(v, 0x118); DPP_STEP_MAX64(v, 0x142); DPP_STEP_MAX64(v, 0x143);
    return v;
}
__device__ inline uint64_t dpp_max64_to7(uint64_t v) {   // valid in lane 7
    DPP_STEP_MAX64(v, 0x111); DPP_STEP_MAX64(v, 0x112); DPP_STEP_MAX64(v, 0x114);
    return v;
}

__global__ __launch_bounds__(FPS_T, 1) void k_fps(
        const void* mask_raw, const float* seed_xyz,
        float4* cp, int* fps_idx,
        const float* crop_w2, unsigned short* w2bf)
{
    const int tid  = threadIdx.x;

    if (blockIdx.x >= B_SZ) {
        // ---- w2bf conversion on idle CUs, overlapped under FPS ----
        // 128 blocks x 512 thr x 8 floats = 524288 = 4*512*256 exactly
        int w = blockIdx.x - B_SZ;
        int i4 = w * 4096 + tid * 8;
        float4 f0 = *(const float4*)&crop_w2[i4];
        float4 f1 = *(const float4*)&crop_w2[i4 + 4];
        ushort4 o0, o1;
        o0.x = f2bf(f0.x); o0.y = f2bf(f0.y); o0.z = f2bf(f0.z); o0.w = f2bf(f0.w);
        o1.x = f2bf(f1.x); o1.y = f2bf(f1.y); o1.z = f2bf(f1.z); o1.w = f2bf(f1.w);
        *(ushort4*)&w2bf[i4] = o0;
        *(ushort4*)&w2bf[i4 + 4] = o1;
        return;
    }

    const int b    = blockIdx.x;
    const int wv   = tid >> 6;
    const int lane = tid & 63;
    const int cpb  = b * 15008;

    __shared__ float4   ptsL[FPS_CAP];         // 131072 B (fallback: pd overlay)
    __shared__ uint64_t s_pubk[2][8];          // main path publish slots
    __shared__ float4   s_pub4[2][8];          // fallback publish
    __shared__ int      s_pubi[2][8];          // fallback publish
    __shared__ int      s_rw[256];             // (k,wave) counts -> exclusive bases
    __shared__ int      s_wt4[4];
    __shared__ int      s_total, s_start, s_vi, s_vf;
    __shared__ float    s_f[3];

    if (tid == 0) { s_start = 0x7fffffff; s_vi = 0; s_vf = 0; }
    __syncthreads();

    // inlined mask-dtype detect (identical semantics to old k_detect)
    {
        int li = 0, lf = 0;
        const unsigned int* mraw = (const unsigned int*)mask_raw;
        for (int i = tid; i < (B_SZ * N_PTS) / 4; i += FPS_T) {
            unsigned int u = mraw[i];
            if (u != 0u && u != 1u) li = 1;
            if (u != 0u && u != 0x3F800000u) lf = 1;
        }
        if (li) atomicOr(&s_vi, 1);
        if (lf) atomicOr(&s_vf, 1);
    }
    __syncthreads();
    const int mode = (s_vi == 0) ? 0 : ((s_vf == 0) ? 1 : 2);

    auto rd_mask = [&](int i) -> bool {
        if (mode == 0) return ((const int*)mask_raw)[b * N_PTS + i] != 0;
        if (mode == 1) return ((const unsigned int*)mask_raw)[b * N_PTS + i] != 0u;
        return ((const unsigned char*)mask_raw)[b * N_PTS + i] != 0;
    };

    // pass 1: per-(k,wave) masked counts via ballot + first masked index
    unsigned mbits = 0;
    int myfirst = 0x7fffffff;
    for (int k = 0; k < 30; ++k) {
        int i = tid + k * FPS_T;
        bool mm = (i < N_PTS) && rd_mask(i);
        if (mm) { if (i < myfirst) myfirst = i; mbits |= 1u << k; }
        unsigned long long bal = __ballot(mm);
        if (lane == 0) s_rw[k * 8 + wv] = __popcll(bal);
    }
    if (myfirst != 0x7fffffff) atomicMin(&s_start, myfirst);
    __syncthreads();

    // exclusive scan over 240 (k,wave) counts (pad to 256; waves 0..3)
    {
        int v = 0, inc = 0;
        if (tid < 256) {
            v = (tid < 240) ? s_rw[tid] : 0;
            inc = v;
            #pragma unroll
            for (int d = 1; d < 64; d <<= 1) {
                int o = __shfl_up(inc, d, 64);
                if (lane >= d) inc += o;
            }
            if (lane == 63) s_wt4[wv] = inc;
        }
        __syncthreads();
        if (tid < 256) {
            int off = 0;
            #pragma unroll
            for (int w = 0; w < 4; ++w) off += (w < wv) ? s_wt4[w] : 0;
            s_rw[tid] = off + inc - v;
            if (tid == 255) s_total = off + inc;
        }
        __syncthreads();
    }
    const int Mc = s_total;
    const int start = s_start;
    if (Mc == 0) {
        for (int m = tid; m < MPT; m += FPS_T) fps_idx[b * MPT + m] = 0;
        return;
    }
    const bool use_fallback = (Mc > FPS_CAP);

    // pass 2: order-preserving compaction (compact idx ascending == orig idx
    // ascending) into LDS ptsL (cp mirror only if fallback will run)
    for (int k = 0; k < 30; ++k) {
        bool mm = (mbits >> k) & 1u;
        unsigned long long bal = __ballot(mm);
        int pos = s_rw[k * 8 + wv] + __popcll(bal & ((1ull << lane) - 1ull));
        if (mm) {
            int i = tid + k * FPS_T;
            float x = seed_xyz[(size_t)(b * N_PTS + i) * 3 + 0];
            float y = seed_xyz[(size_t)(b * N_PTS + i) * 3 + 1];
            float z = seed_xyz[(size_t)(b * N_PTS + i) * 3 + 2];
            float4 v4 = make_float4(x, y, z, __int_as_float(i));
            if (use_fallback) cp[cpb + pos] = v4;
            if (pos < FPS_CAP) ptsL[pos] = v4;
            if (i == start) { s_f[0] = x; s_f[1] = y; s_f[2] = z; }
        }
    }
    __threadfence_block();
    __syncthreads();

    if (!use_fallback) {
        // ========== main path: register-resident points, packed-fp32 loop ==========
        f32x2    px2[8], py2[8], pz2[8], pd2[8];
        unsigned plo[FPS_K];                  // ~compact_idx (tie-break key lo)
        #pragma unroll
        for (int j = 0; j < 8; ++j) {
            int c0 = tid + (2 * j) * FPS_T;   // c < 8192 always
            int c1 = tid + (2 * j + 1) * FPS_T;
            bool v0 = c0 < Mc, v1 = c1 < Mc;
            float4 t0 = ptsL[c0];
            float4 t1 = ptsL[c1];
            px2[j].x = v0 ? t0.x : 1e9f;  px2[j].y = v1 ? t1.x : 1e9f;
            py2[j].x = v0 ? t0.y : 1e9f;  py2[j].y = v1 ? t1.y : 1e9f;
            pz2[j].x = v0 ? t0.z : 1e9f;  pz2[j].y = v1 ? t1.z : 1e9f;
            pd2[j].x = v0 ? 1e10f : 0.f;  pd2[j].y = v1 ? 1e10f : 0.f;
            plo[2*j]   = v0 ? ~(unsigned)c0 : 0u;
            plo[2*j+1] = v1 ? ~(unsigned)c1 : 0u;
        }

        // first selection = compact idx 0 = first masked orig index
        float4 f0 = ptsL[0];
        float fx = f0.x, fy = f0.y, fz = f0.z;
        int widx = __float_as_int(f0.w);
        int par = 0;

        #pragma unroll 1
        for (int m = 0; m < MPT; ++m) {
            if (tid == 0) fps_idx[b * MPT + m] = widx;

            uint64_t best = 0;
            {
                // contract(off): keep pk_mul + pk_add separate -> bit-identical
                // to scalar __fmul_rn/__fadd_rn with assoc ((dx2+dy2)+dz2)
                #pragma clang fp contract(off)
                const f32x2 f2x = {fx, fx};
                const f32x2 f2y = {fy, fy};
                const f32x2 f2z = {fz, fz};
                #pragma unroll
                for (int j = 0; j < 8; ++j) {
                    f32x2 dx = px2[j] - f2x;
                    f32x2 dy = py2[j] - f2y;
                    f32x2 dz = pz2[j] - f2z;
                    f32x2 d  = dx * dx + dy * dy + dz * dz;
                    f32x2 nd;
                    nd.x = fminf(pd2[j].x, d.x);
                    nd.y = fminf(pd2[j].y, d.y);
                    pd2[j] = nd;
                    uint64_t c0 = ((uint64_t)__float_as_uint(nd.x) << 32) | plo[2*j];
                    uint64_t c1 = ((uint64_t)__float_as_uint(nd.y) << 32) | plo[2*j+1];
                    best = c0 > best ? c0 : best;
                    best = c1 > best ? c1 : best;
                }
            }
            best = dpp_max64_to63(best);
            if (lane == 63) s_pubk[par][wv] = best;
            __syncthreads();
            uint64_t pk = s_pubk[par][lane & 7];
            pk = dpp_max64_to7(pk);
            unsigned glo = (unsigned)__builtin_amdgcn_readlane((int)(unsigned)pk, 7);
            unsigned ci  = ~glo;
            float4 g4 = ptsL[ci];
            fx = g4.x; fy = g4.y; fz = g4.z;
            widx = __float_as_int(g4.w);
            par ^= 1;
        }
    } else {
        // ============ fallback (Mc > 8192): L2 coords, LDS pd ============
        const int L = (Mc + FPS_T - 1) / FPS_T;
        float* pdL = (float*)ptsL;             // Mc <= 15000 -> 60 KB
        for (int c = tid; c < Mc; c += FPS_T) pdL[c] = 1e10f;
        if (lane == 0) {
            s_pub4[0][wv] = make_float4(-1.f, 0.f, 0.f, 0.f);
            s_pub4[1][wv] = make_float4(-1.f, 0.f, 0.f, 0.f);
            s_pubi[0][wv] = 0x7fffffff;
            s_pubi[1][wv] = 0x7fffffff;
        }
        __syncthreads();
        float fx = s_f[0], fy = s_f[1], fz = s_f[2];
        int widx = start;
        int par = 0;
        for (int m = 0; m < MPT; ++m) {
            if (tid == 0) fps_idx[b * MPT + m] = widx;
            float nv = -1.f; int ni = 0x7fffffff;
            float nx = 0.f, ny = 0.f, nz = 0.f;
            for (int k = 0; k < L; ++k) {
                int c = tid * L + k;
                if (c < Mc) {
                    float4 v = cp[cpb + c];
                    float dx = __fsub_rn(v.x, fx);
                    float dy = __fsub_rn(v.y, fy);
                    float dz = __fsub_rn(v.z, fz);
                    float d  = __fadd_rn(__fadd_rn(__fmul_rn(dx, dx), __fmul_rn(dy, dy)),
                                         __fmul_rn(dz, dz));
                    float nd = fminf(pdL[c], d);
                    pdL[c] = nd;
                    int oi = __float_as_int(v.w);
                    bool bt = (nd > nv) || (nd == nv && oi < ni);
                    nv = bt ? nd : nv; ni = bt ? oi : ni;
                    nx = bt ? v.x : nx; ny = bt ? v.y : ny; nz = bt ? v.z : nz;
                }
            }
            unsigned vb = (nv >= 0.f) ? __float_as_uint(nv) : 0u;
            unsigned wmax = (unsigned)__builtin_amdgcn_readlane((int)dpp_max_u32(vb), 63);
            int icand = (vb == wmax) ? ni : 0x7fffffff;
            int wmin = __builtin_amdgcn_readlane(dpp_min_i32(icand), 63);
            if ((vb == wmax) && (ni == wmin) && vb != 0u) {
                s_pub4[par][wv] = make_float4(nv, nx, ny, nz);
                s_pubi[par][wv] = ni;
            }
            __syncthreads();
            {
                float bvv = -2.f; int bii = 0x7fffffff;
                float nfx = 0.f, nfy = 0.f, nfz = 0.f;
                #pragma unroll
                for (int w = 0; w < 8; ++w) {
                    float4 c4 = s_pub4[par][w];
                    int ci2 = s_pubi[par][w];
                    bool bt = (c4.x > bvv) || (c4.x == bvv && ci2 < bii);
                    bvv = bt ? c4.x : bvv; bii = bt ? ci2 : bii;
                    nfx = bt ? c4.y : nfx; nfy = bt ? c4.z : nfy; nfz = bt ? c4.w : nfz;
                }
                fx = nfx; fy = nfy; fz = nfz; widx = bii;
            }
            par ^= 1;
        }
    }
}

// ---------------------------------------------------------------- gathers
__global__ void k_gather(const float* seed_features, const float* seed_xyz,
                         const int* fps_idx, float* feat_g, float* xyz_g)
{
    int e = blockIdx.x;
    if (e < B_SZ * CSEED) {
        int b = e >> 9, c = e & (CSEED - 1);
        const float* src = seed_features + (size_t)(b * CSEED + c) * N_PTS;
        float* dst = feat_g + (size_t)(b * CSEED + c) * MPT;
        const int* idx = fps_idx + b * MPT;
        for (int m = threadIdx.x; m < MPT; m += blockDim.x) dst[m] = src[idx[m]];
    } else {
        int b = e - B_SZ * CSEED;
        const int* idx = fps_idx + b * MPT;
        for (int m = threadIdx.x; m < MPT; m += blockDim.x) {
            int p = idx[m];
            xyz_g[(size_t)(b * MPT + m) * 3 + 0] = seed_xyz[(size_t)(b * N_PTS + p) * 3 + 0];
            xyz_g[(size_t)(b * MPT + m) * 3 + 1] = seed_xyz[(size_t)(b * N_PTS + p) * 3 + 1];
            xyz_g[(size_t)(b * MPT + m) * 3 + 2] = seed_xyz[(size_t)(b * N_PTS + p) * 3 + 2];
        }
    }
}

// ---------------------------------------------------------------- F1T + select fused
// blocks [0,256): F1T = feat_g^T * W1f^T + b1  (p-tile 32 -> fills 256 CUs)
// blocks [256,768): local coords + neighbor select
__global__ __launch_bounds__(256) void k_f1sel(
        const float* feat_g, const float* crop_w1, const float* crop_b1, float* f1t,
        const float* xyz_g, const float* views_rot, int* sel_idx, float* sel_xyz)
{
    __shared__ float A[16][32];
    __shared__ float Bm[16][256];
    __shared__ float s_zloc[4][3];
    __shared__ int   s_padk[4][4];
    __shared__ float s_padx[4][4][3];

    const int tid = threadIdx.x;

    if (blockIdx.x < 256) {
        const int blk = blockIdx.x;
        const int pt = blk & 31;               // 32 p-tiles of 32
        const int b  = (blk >> 5) & 1;
        const int s  = blk >> 6;
        const int p0 = pt * 32;
        const int pg = tid & 7, og = tid >> 3; // p: 8x4, o: 32x8
        float acc[4][8];
        #pragma unroll
        for (int i = 0; i < 4; ++i)
            #pragma unroll
            for (int j = 0; j < 8; ++j) acc[i][j] = 0.f;

        for (int kc = 0; kc < CSEED; kc += 16) {
            __syncthreads();
            {
                int r = tid >> 4, pp = (tid & 15) * 2;
                *(float2*)&A[r][pp] =
                    *(const float2*)&feat_g[(size_t)(b * CSEED + kc + r) * MPT + p0 + pp];
                #pragma unroll
                for (int r2 = 0; r2 < 16; ++r2)
                    Bm[r2][tid] = crop_w1[(size_t)(s * 256 + tid) * 515 + 3 + kc + r2];
            }
            __syncthreads();
            #pragma unroll
            for (int r = 0; r < 16; ++r) {
                float4 a4 = *(const float4*)&A[r][pg * 4];
                float av[4] = {a4.x, a4.y, a4.z, a4.w};
                float bv[8];
                #pragma unroll
                for (int q = 0; q < 2; ++q) {
                    float4 b4 = *(const float4*)&Bm[r][og * 8 + q * 4];
                    bv[q*4+0] = b4.x; bv[q*4+1] = b4.y; bv[q*4+2] = b4.z; bv[q*4+3] = b4.w;
                }
                #pragma unroll
                for (int i = 0; i < 4; ++i)
                    #pragma unroll
                    for (int j = 0; j < 8; ++j)
                        acc[i][j] += av[i] * bv[j];
            }
        }
        #pragma unroll
        for (int i = 0; i < 4; ++i) {
            size_t row = (size_t)((s * B_SZ + b) * MPT + p0 + pg * 4 + i) * 256;
            #pragma unroll
            for (int q = 0; q < 2; ++q) {
                float4 o4;
                o4.x = acc[i][q*4+0] + crop_b1[s*256 + og*8 + q*4+0];
                o4.y = acc[i][q*4+1] + crop_b1[s*256 + og*8 + q*4+1];
                o4.z = acc[i][q*4+2] + crop_b1[s*256 + og*8 + q*4+2];
                o4.w = acc[i][q*4+3] + crop_b1[s*256 + og*8 + q*4+3];
                *(float4*)&f1t[row + og * 8 + q * 4] = o4;
            }
        }
    } else {
        const int wv = tid >> 6;
        const int lane = tid & 63;
        const int gj = (blockIdx.x - 256) * 4 + wv;
        const int b = gj >> 10, j = gj & (MPT - 1);

        const float cx = xyz_g[(size_t)(b * MPT + j) * 3 + 0];
        const float cy = xyz_g[(size_t)(b * MPT + j) * 3 + 1];
        const float cz = xyz_g[(size_t)(b * MPT + j) * 3 + 2];
        const float* R = views_rot + (size_t)(b * MPT + j) * 9;
        const float r00 = R[0], r01 = R[1], r02 = R[2];
        const float r10 = R[3], r11 = R[4], r12 = R[5];
        const float r20 = R[6], r21 = R[7], r22 = R[8];

        const float R2C[4] = { (float)(0.025 * 0.025), (float)(0.0375 * 0.0375),
                               (float)(0.05 * 0.05),   (float)(0.075 * 0.075) };
        const int NSs[4] = {16, 32, 32, 64};

        int cnt[4] = {0, 0, 0, 0};

        for (int ch = 0; ch < 16; ++ch) {
            int k = ch * 64 + lane;
            float x = xyz_g[(size_t)(b * MPT + k) * 3 + 0];
            float y = xyz_g[(size_t)(b * MPT + k) * 3 + 1];
            float z = xyz_g[(size_t)(b * MPT + k) * 3 + 2];
            float rx = __fsub_rn(x, cx), ry = __fsub_rn(y, cy), rz = __fsub_rn(z, cz);
            float l0 = __fadd_rn(__fadd_rn(__fmul_rn(rx, r00), __fmul_rn(ry, r10)), __fmul_rn(rz, r20));
            float l1 = __fadd_rn(__fadd_rn(__fmul_rn(rx, r01), __fmul_rn(ry, r11)), __fmul_rn(rz, r21));
            float l2 = __fadd_rn(__fadd_rn(__fmul_rn(rx, r02), __fmul_rn(ry, r12)), __fmul_rn(rz, r22));
            float r2 = __fadd_rn(__fmul_rn(l1, l1), __fmul_rn(l2, l2));
            bool inh = (l0 >= HMINF) && (l0 <= HMAXF);
            if (ch == 0 && lane == 0) { s_zloc[wv][0] = l0; s_zloc[wv][1] = l1; s_zloc[wv][2] = l2; }
            #pragma unroll
            for (int sc = 0; sc < 4; ++sc) {
                bool v = inh && (r2 < R2C[sc]);
                unsigned long long bal = __ballot(v);
                int pre = __popcll(bal & ((1ull << lane) - 1ull));
                int p = cnt[sc] + pre;
                if (v && p < NSs[sc]) {
                    size_t sb = ((size_t)(sc * B_SZ + b) * MPT + j) * 64 + p;
                    sel_idx[sb] = k;
                    sel_xyz[sb * 3 + 0] = l0;
                    sel_xyz[sb * 3 + 1] = l1;
                    sel_xyz[sb * 3 + 2] = l2;
                    if (p == 0) {
                        s_padk[wv][sc] = k;
                        s_padx[wv][sc][0] = l0; s_padx[wv][sc][1] = l1; s_padx[wv][sc][2] = l2;
                    }
                }
                cnt[sc] += __popcll(bal);
            }
        }
        __syncthreads();
        #pragma unroll
        for (int sc = 0; sc < 4; ++sc) {
            int cs = cnt[sc];
            int pk; float a0, a1, a2;
            if (cs > 0) { pk = s_padk[wv][sc]; a0 = s_padx[wv][sc][0]; a1 = s_padx[wv][sc][1]; a2 = s_padx[wv][sc][2]; }
            else        { pk = 0; a0 = s_zloc[wv][0]; a1 = s_zloc[wv][1]; a2 = s_zloc[wv][2]; }
            for (int n = cs + lane; n < NSs[sc]; n += 64) {
                size_t sb = ((size_t)(sc * B_SZ + b) * MPT + j) * 64 + n;
                sel_idx[sb] = pk;
                sel_xyz[sb * 3 + 0] = a0; sel_xyz[sb * 3 + 1] = a1; sel_xyz[sb * 3 + 2] = a2;
            }
        }
    }
}

// ---------------------------------------------------------------- crop MLP via bf16 MFMA
// wave wv owns o-tiles [8wv, 8wv+8) over ALL 64 h1 cols; W2 read once/block.
__global__ __launch_bounds__(256) void k_crop(
        const float* f1t, const float* crop_w1, const unsigned short* w2bf,
        const float* crop_b2, const int* sel_idx, const float* sel_xyz, float* vp_cat)
{
    const int blk0 = blockIdx.x;
    int s, log2ns, base;
    if (blk0 < 512)       { s = 0; log2ns = 4; base = 0; }
    else if (blk0 < 1536) { s = 1; log2ns = 5; base = 512; }
    else if (blk0 < 2560) { s = 2; log2ns = 5; base = 1536; }
    else                  { s = 3; log2ns = 6; base = 2560; }
    const int ns = 1 << log2ns;
    const int rel = blk0 - base;

    const int tid = threadIdx.x;
    const int jt = 64 >> log2ns;
    const int nj = MPT / jt;
    const int b = rel / nj;
    const int jbase = (rel % nj) * jt;

    __shared__ unsigned short h1T[64 * 264];   // [col][c] bf16, stride 264
    __shared__ float w1xa[3 * 256];

    for (int i = tid; i < 768; i += 256) {
        int a = i >> 8, o = i & 255;
        w1xa[i] = crop_w1[(size_t)(s * 256 + o) * 515 + a];
    }
    __syncthreads();

    // phase 1: h1 = relu(f1row + W1x*xyz) -> bf16 -> h1T
    {
        const int col = tid & 63;
        const int cq = tid >> 6;
        const int jl = col >> log2ns;
        const int nn = col & (ns - 1);
        const size_t sb = ((size_t)(s * B_SZ + b) * MPT + jbase + jl) * 64 + nn;
        const int p = sel_idx[sb];
        const float gx = sel_xyz[sb * 3 + 0];
        const float gy = sel_xyz[sb * 3 + 1];
        const float gz = sel_xyz[sb * 3 + 2];
        const float* f1row = f1t + (size_t)((s * B_SZ + b) * MPT + p) * 256;
        #pragma unroll
        for (int c4 = 0; c4 < 16; ++c4) {
            int c0 = cq * 64 + c4 * 4;
            float4 fv = *(const float4*)&f1row[c0];
            float v0 = fmaxf(fv.x + w1xa[c0+0]*gx + w1xa[256+c0+0]*gy + w1xa[512+c0+0]*gz, 0.f);
            float v1 = fmaxf(fv.y + w1xa[c0+1]*gx + w1xa[256+c0+1]*gy + w1xa[512+c0+1]*gz, 0.f);
            float v2 = fmaxf(fv.z + w1xa[c0+2]*gx + w1xa[256+c0+2]*gy + w1xa[512+c0+2]*gz, 0.f);
            float v3 = fmaxf(fv.w + w1xa[c0+3]*gx + w1xa[256+c0+3]*gy + w1xa[512+c0+3]*gz, 0.f);
            unsigned lo = (unsigned)f2bf(v0) | ((unsigned)f2bf(v1) << 16);
            unsigned hi = (unsigned)f2bf(v2) | ((unsigned)f2bf(v3) << 16);
            *(uint2*)&h1T[col * 264 + c0] = make_uint2(lo, hi);
        }
    }
    __syncthreads();

    // phase 2: wave wv -> o-tiles [8wv, 8wv+8), all 64 cols via 4 A-groups
    {
        const int wv = tid >> 6;
        const int lane = tid & 63;
        const int lm = lane & 15, lq = lane >> 4;
        const unsigned short* wbase = w2bf + (size_t)s * 512 * 256;

        #pragma unroll 1
        for (int t = 0; t < 8; ++t) {
            const int ot = wv * 8 + t;
            bf16x8 bb[8];
            #pragma unroll
            for (int kk = 0; kk < 8; ++kk)
                bb[kk] = *(const bf16x8*)&wbase[(size_t)(ot * 16 + lm) * 256 + kk * 32 + lq * 8];

            float mg[4];
            #pragma unroll
            for (int g = 0; g < 4; ++g) {
                f32x4 acc = {0.f, 0.f, 0.f, 0.f};
                #pragma unroll
                for (int kk = 0; kk < 8; ++kk) {
                    bf16x8 af = *(const bf16x8*)&h1T[(g * 16 + lm) * 264 + kk * 32 + lq * 8];
                    acc = __builtin_amdgcn_mfma_f32_16x16x32_bf16(af, bb[kk], acc, 0, 0, 0);
                }
                mg[g] = fmaxf(fmaxf(acc[0], acc[1]), fmaxf(acc[2], acc[3]));
            }

            if (log2ns == 4) {                 // jt=4: group == center
                #pragma unroll
                for (int g = 0; g < 4; ++g) {
                    float v = mg[g];
                    v = fmaxf(v, __shfl_xor(v, 16, 64));
                    v = fmaxf(v, __shfl_xor(v, 32, 64));
                    mg[g] = v;
                }
                if (lane < 16) {
                    int o = ot * 16 + lane;
                    float b2v = crop_b2[s * 512 + o];
                    size_t rowb = ((size_t)(b * 4 + s) * 512 + o) * MPT + jbase;
                    vp_cat[rowb + 0] = fmaxf(mg[0] + b2v, 0.f);
                    vp_cat[rowb + 1] = fmaxf(mg[1] + b2v, 0.f);
                    vp_cat[rowb + 2] = fmaxf(mg[2] + b2v, 0.f);
                    vp_cat[rowb + 3] = fmaxf(mg[3] + b2v, 0.f);
                }
            } else if (log2ns == 5) {          // jt=2: centers = group pairs
                float c0 = fmaxf(mg[0], mg[1]);
                float c1 = fmaxf(mg[2], mg[3]);
                c0 = fmaxf(c0, __shfl_xor(c0, 16, 64));
                c0 = fmaxf(c0, __shfl_xor(c0, 32, 64));
                c1 = fmaxf(c1, __shfl_xor(c1, 16, 64));
                c1 = fmaxf(c1, __shfl_xor(c1, 32, 64));
                if (lane < 16) {
                    int o = ot * 16 + lane;
                    float b2v = crop_b2[s * 512 + o];
                    size_t rowb = ((size_t)(b * 4 + s) * 512 + o) * MPT + jbase;
                    vp_cat[rowb + 0] = fmaxf(c0 + b2v, 0.f);
                    vp_cat[rowb + 1] = fmaxf(c1 + b2v, 0.f);
                }
            } else {                           // jt=1: one center, all groups
                float c0 = fmaxf(fmaxf(mg[0], mg[1]), fmaxf(mg[2], mg[3]));
                c0 = fmaxf(c0, __shfl_xor(c0, 16, 64));
                c0 = fmaxf(c0, __shfl_xor(c0, 32, 64));
                if (lane < 16) {
                    int o = ot * 16 + lane;
                    vp_cat[((size_t)(b * 4 + s) * 512 + o) * MPT + jbase] =
                        fmaxf(c0 + crop_b2[s * 512 + o], 0.f);
                }
            }
        }
    }
}

// ---------------------------------------------------------------- fuse + gate + output
// 512 blocks (o-tile 64 x m-tile 32), 2 blocks/CU. K-chunk 32.
__global__ __launch_bounds__(256, 2) void k_out(
        const float* vp_cat, const float* feat_g,
        const float* fuse_w, const float* fuse_b,
        const float* gate_w, const float* gate_b, float* out)
{
    const int blk = blockIdx.x;
    const int mt = blk & 31;                   // 32 m-tiles of 32
    const int ot = (blk >> 5) & 7;             // 8 o-tiles of 64
    const int b  = blk >> 8;
    const int o0b = ot * 64, m0b = mt * 32;
    __shared__ float A[32 * 64];               // 8 KB
    __shared__ float Bm[32 * 32];              // 4 KB
    const int tid = threadIdx.x;
    const int og = tid >> 3;                   // 32 groups x 2 o
    const int mg = tid & 7;                    // 8 groups x 4 m
    float acc1[2][4], acc2[2][4];
    #pragma unroll
    for (int i = 0; i < 2; ++i)
        #pragma unroll
        for (int jq = 0; jq < 4; ++jq) { acc1[i][jq] = 0.f; acc2[i][jq] = 0.f; }

    for (int kc = 0; kc < 2048; kc += 32) {
        __syncthreads();
        {
            int oo = tid & 63, r8 = (tid >> 6) * 8;
            const float* srow = &fuse_w[(size_t)(o0b + oo) * 2048 + kc + r8];
            float4 u0 = *(const float4*)srow;
            float4 u1 = *(const float4*)(srow + 4);
            A[(r8 + 0) * 64 + oo] = u0.x; A[(r8 + 1) * 64 + oo] = u0.y;
            A[(r8 + 2) * 64 + oo] = u0.z; A[(r8 + 3) * 64 + oo] = u0.w;
            A[(r8 + 4) * 64 + oo] = u1.x; A[(r8 + 5) * 64 + oo] = u1.y;
            A[(r8 + 6) * 64 + oo] = u1.z; A[(r8 + 7) * 64 + oo] = u1.w;
            int r = tid >> 3, mm = (tid & 7) * 4;
            *(float4*)&Bm[r * 32 + mm] =
                *(const float4*)&vp_cat[((size_t)b * 2048 + kc + r) * MPT + m0b + mm];
        }
        __syncthreads();
        #pragma unroll
        for (int r = 0; r < 32; ++r) {
            float2 a0 = *(const float2*)&A[r * 64 + og * 2];
            float4 bb = *(const float4*)&Bm[r * 32 + mg * 4];
            float av[2] = {a0.x, a0.y};
            float bv[4] = {bb.x, bb.y, bb.z, bb.w};
            #pragma unroll
            for (int oi = 0; oi < 2; ++oi)
                #pragma unroll
                for (int mi = 0; mi < 4; ++mi)
                    acc1[oi][mi] += av[oi] * bv[mi];
        }
    }
    for (int kc = 0; kc < 512; kc += 32) {
        __syncthreads();
        {
            int oo = tid & 63, r8 = (tid >> 6) * 8;
            const float* srow = &gate_w[(size_t)(o0b + oo) * 512 + kc + r8];
            float4 u0 = *(const float4*)srow;
            float4 u1 = *(const float4*)(srow + 4);
            A[(r8 + 0) * 64 + oo] = u0.x; A[(r8 + 1) * 64 + oo] = u0.y;
            A[(r8 + 2) * 64 + oo] = u0.z; A[(r8 + 3) * 64 + oo] = u0.w;
            A[(r8 + 4) * 64 + oo] = u1.x; A[(r8 + 5) * 64 + oo] = u1.y;
            A[(r8 + 6) * 64 + oo] = u1.z; A[(r8 + 7) * 64 + oo] = u1.w;
            int r = tid >> 3, mm = (tid & 7) * 4;
            *(float4*)&Bm[r * 32 + mm] =
                *(const float4*)&feat_g[((size_t)b * CSEED + kc + r) * MPT + m0b + mm];
        }
        __syncthreads();
        #pragma unroll
        for (int r = 0; r < 32; ++r) {
            float2 a0 = *(const float2*)&A[r * 64 + og * 2];
            float4 bb = *(const float4*)&Bm[r * 32 + mg * 4];
            float av[2] = {a0.x, a0.y};
            float bv[4] = {bb.x, bb.y, bb.z, bb.w};
            #pragma unroll
            for (int oi = 0; oi < 2; ++oi)
                #pragma unroll
                for (int mi = 0; mi < 4; ++mi)
                    acc2[oi][mi] += av[oi] * bv[mi];
        }
    }
    #pragma unroll
    for (int oi = 0; oi < 2; ++oi) {
        int o = o0b + og * 2 + oi;
        float fb = fuse_b[o], gb = gate_b[o];
        #pragma unroll
        for (int mi = 0; mi < 4; ++mi) {
            int m = m0b + mg * 4 + mi;
            float f = acc1[oi][mi] + fb;
            float gl = acc2[oi][mi] + gb;
            float gt = 1.f / (1.f + __expf(-gl));
            float fg = feat_g[((size_t)b * CSEED + o) * MPT + m];
            out[((size_t)b * CSEED + o) * MPT + m] = f + gt * fg;
        }
    }
}

// ---------------------------------------------------------------- launcher
extern "C" void kernel_launch(void* const* d_in, const int* in_sizes, int n_in,
                              void* d_out, int out_size, void* d_ws, size_t ws_size,
                              hipStream_t stream) {
    const float* seed_xyz      = (const float*)d_in[0];
    const float* seed_features = (const float*)d_in[1];
    const void*  mask_raw      = d_in[2];
    const float* views_rot     = (const float*)d_in[3];
    const float* crop_w1       = (const float*)d_in[4];
    const float* crop_b1       = (const float*)d_in[5];
    const float* crop_w2       = (const float*)d_in[6];
    const float* crop_b2       = (const float*)d_in[7];
    const float* fuse_w        = (const float*)d_in[8];
    const float* fuse_b        = (const float*)d_in[9];
    const float* gate_w        = (const float*)d_in[10];
    const float* gate_b        = (const float*)d_in[11];
    float* out = (float*)d_out;

    char* ws = (char*)d_ws;
    size_t off = 0;
    auto alloc = [&](size_t bytes) -> void* {
        void* p = ws + off;
        off = (off + bytes + 255) & ~(size_t)255;
        return p;
    };
    int*            fpsidx = (int*)            alloc((size_t)B_SZ * MPT * 4);
    float4*         cp     = (float4*)         alloc((size_t)B_SZ * 15008 * 16);
    float*          xyzg   = (float*)          alloc((size_t)B_SZ * MPT * 3 * 4);
    float*          featg  = (float*)          alloc((size_t)B_SZ * CSEED * MPT * 4);
    float*          f1t    = (float*)          alloc((size_t)4 * B_SZ * MPT * 256 * 4);
    int*            selidx = (int*)            alloc((size_t)4 * B_SZ * MPT * 64 * 4);
    float*          selxyz = (float*)          alloc((size_t)4 * B_SZ * MPT * 64 * 3 * 4);
    unsigned short* w2bf   = (unsigned short*) alloc((size_t)4 * 512 * 256 * 2);
    float*          vpcat  = (float*)          alloc((size_t)B_SZ * 4 * 512 * MPT * 4);

    k_fps<<<B_SZ + W2_BLKS, FPS_T, 0, stream>>>(mask_raw, seed_xyz, cp, fpsidx, crop_w2, w2bf);
    k_gather<<<B_SZ * CSEED + B_SZ, 256, 0, stream>>>(
        seed_features, seed_xyz, fpsidx, featg, xyzg);
    k_f1sel<<<256 + (B_SZ * MPT) / 4, 256, 0, stream>>>(
        featg, crop_w1, crop_b1, f1t, xyzg, views_rot, selidx, selxyz);
    k_crop<<<4608, 256, 0, stream>>>(f1t, crop_w1, w2bf, crop_b2, selidx, selxyz, vpcat);
    k_out<<<512, 256, 0, stream>>>(vpcat, featg, fuse_w, fuse_b, gate_w, gate_b, out);
}

// Round 15
// 1279.887 us; speedup vs baseline: 1.0880x; 1.0880x over previous
//
#include <hip/hip_runtime.h>
#include <stdint.h>
#include <stddef.h>

#define B_SZ   2
#define N_PTS  15000
#define MPT    1024
#define CSEED  512
#define HMINF (-0.02f)
#define HMAXF (0.06f)

typedef __attribute__((ext_vector_type(8))) short bf16x8;
typedef __attribute__((ext_vector_type(4))) float f32x4;

__device__ inline unsigned short f2bf(float f) {
    unsigned u = __float_as_uint(f);
    unsigned r = (u + 0x7fffu + ((u >> 16) & 1u)) >> 16;   // RNE, finite inputs
    return (unsigned short)r;
}

// ---------------------------------------------------------------- masked FPS v11 + inlined detect + w2bf co-grid
// Flat register-resident FPS (8 waves, 2/SIMD = proven optimum; v14 packed-
// fp32 attempt REGRESSED 811->910us: f32x2 scalarized with pack/unpack
// overhead -> reverted to scalar v13 form, 811us verified).
// Blocks >= B_SZ convert W2->bf16 on otherwise-idle CUs, overlapped under FPS.
#define FPS_T     512
#define FPS_CAP   8192          // 16 slots x 512 thr; Mc>CAP -> exact fallback
#define FPS_K     16
#define W2_BLKS   128           // 128 x 512 x 8 = 524288 floats exactly

__device__ inline unsigned dpp_max_u32(unsigned v) {   // valid in lane 63 (fallback)
    unsigned t;
    t = (unsigned)__builtin_amdgcn_update_dpp(0, (int)v, 0x111, 0xf, 0xf, false); v = v > t ? v : t;
    t = (unsigned)__builtin_amdgcn_update_dpp(0, (int)v, 0x112, 0xf, 0xf, false); v = v > t ? v : t;
    t = (unsigned)__builtin_amdgcn_update_dpp(0, (int)v, 0x114, 0xf, 0xf, false); v = v > t ? v : t;
    t = (unsigned)__builtin_amdgcn_update_dpp(0, (int)v, 0x118, 0xf, 0xf, false); v = v > t ? v : t;
    t = (unsigned)__builtin_amdgcn_update_dpp(0, (int)v, 0x142, 0xf, 0xf, false); v = v > t ? v : t;
    t = (unsigned)__builtin_amdgcn_update_dpp(0, (int)v, 0x143, 0xf, 0xf, false); v = v > t ? v : t;
    return v;
}
__device__ inline int dpp_min_i32(int v) {             // valid in lane 63 (fallback)
    int t;
    t = __builtin_amdgcn_update_dpp(0x7fffffff, v, 0x111, 0xf, 0xf, false); v = v < t ? v : t;
    t = __builtin_amdgcn_update_dpp(0x7fffffff, v, 0x112, 0xf, 0xf, false); v = v < t ? v : t;
    t = __builtin_amdgcn_update_dpp(0x7fffffff, v, 0x114, 0xf, 0xf, false); v = v < t ? v : t;
    t = __builtin_amdgcn_update_dpp(0x7fffffff, v, 0x118, 0xf, 0xf, false); v = v < t ? v : t;
    t = __builtin_amdgcn_update_dpp(0x7fffffff, v, 0x142, 0xf, 0xf, false); v = v < t ? v : t;
    t = __builtin_amdgcn_update_dpp(0x7fffffff, v, 0x143, 0xf, 0xf, false); v = v < t ? v : t;
    return v;
}

#define DPP_STEP_MAX64(v, ctrl)                                                              \
    {                                                                                        \
        unsigned _hi = (unsigned)((v) >> 32), _lo = (unsigned)(v);                           \
        unsigned _th = (unsigned)__builtin_amdgcn_update_dpp(0, (int)_hi, ctrl, 0xf, 0xf, false); \
        unsigned _tl = (unsigned)__builtin_amdgcn_update_dpp(0, (int)_lo, ctrl, 0xf, 0xf, false); \
        uint64_t _t = ((uint64_t)_th << 32) | _tl;                                           \
        (v) = _t > (v) ? _t : (v);                                                           \
    }

__device__ inline uint64_t dpp_max64_to63(uint64_t v) {  // valid in lane 63
    DPP_STEP_MAX64(v, 0x111); DPP_STEP_MAX64(v, 0x112); DPP_STEP_MAX64(v, 0x114);
    DPP_STEP_MAX64(v, 0x118); DPP_STEP_MAX64(v, 0x142); DPP_STEP_MAX64(v, 0x143);
    return v;
}
__device__ inline uint64_t dpp_max64_to7(uint64_t v) {   // valid in lane 7
    DPP_STEP_MAX64(v, 0x111); DPP_STEP_MAX64(v, 0x112); DPP_STEP_MAX64(v, 0x114);
    return v;
}

__global__ __launch_bounds__(FPS_T, 1) void k_fps(
        const void* mask_raw, const float* seed_xyz,
        float4* cp, int* fps_idx,
        const float* crop_w2, unsigned short* w2bf)
{
    const int tid  = threadIdx.x;

    if (blockIdx.x >= B_SZ) {
        // ---- w2bf conversion on idle CUs, overlapped under FPS ----
        // 128 blocks x 512 thr x 8 floats = 524288 = 4*512*256 exactly
        int w = blockIdx.x - B_SZ;
        int i4 = w * 4096 + tid * 8;
        float4 f0 = *(const float4*)&crop_w2[i4];
        float4 f1 = *(const float4*)&crop_w2[i4 + 4];
        ushort4 o0, o1;
        o0.x = f2bf(f0.x); o0.y = f2bf(f0.y); o0.z = f2bf(f0.z); o0.w = f2bf(f0.w);
        o1.x = f2bf(f1.x); o1.y = f2bf(f1.y); o1.z = f2bf(f1.z); o1.w = f2bf(f1.w);
        *(ushort4*)&w2bf[i4] = o0;
        *(ushort4*)&w2bf[i4 + 4] = o1;
        return;
    }

    const int b    = blockIdx.x;
    const int wv   = tid >> 6;
    const int lane = tid & 63;
    const int cpb  = b * 15008;

    __shared__ float4   ptsL[FPS_CAP];         // 131072 B (fallback: pd overlay)
    __shared__ uint64_t s_pubk[2][8];          // main path publish slots
    __shared__ float4   s_pub4[2][8];          // fallback publish
    __shared__ int      s_pubi[2][8];          // fallback publish
    __shared__ int      s_rw[256];             // (k,wave) counts -> exclusive bases
    __shared__ int      s_wt4[4];
    __shared__ int      s_total, s_start, s_vi, s_vf;
    __shared__ float    s_f[3];

    if (tid == 0) { s_start = 0x7fffffff; s_vi = 0; s_vf = 0; }
    __syncthreads();

    // inlined mask-dtype detect (identical semantics to old k_detect)
    {
        int li = 0, lf = 0;
        const unsigned int* mraw = (const unsigned int*)mask_raw;
        for (int i = tid; i < (B_SZ * N_PTS) / 4; i += FPS_T) {
            unsigned int u = mraw[i];
            if (u != 0u && u != 1u) li = 1;
            if (u != 0u && u != 0x3F800000u) lf = 1;
        }
        if (li) atomicOr(&s_vi, 1);
        if (lf) atomicOr(&s_vf, 1);
    }
    __syncthreads();
    const int mode = (s_vi == 0) ? 0 : ((s_vf == 0) ? 1 : 2);

    auto rd_mask = [&](int i) -> bool {
        if (mode == 0) return ((const int*)mask_raw)[b * N_PTS + i] != 0;
        if (mode == 1) return ((const unsigned int*)mask_raw)[b * N_PTS + i] != 0u;
        return ((const unsigned char*)mask_raw)[b * N_PTS + i] != 0;
    };

    // pass 1: per-(k,wave) masked counts via ballot + first masked index
    unsigned mbits = 0;
    int myfirst = 0x7fffffff;
    for (int k = 0; k < 30; ++k) {
        int i = tid + k * FPS_T;
        bool mm = (i < N_PTS) && rd_mask(i);
        if (mm) { if (i < myfirst) myfirst = i; mbits |= 1u << k; }
        unsigned long long bal = __ballot(mm);
        if (lane == 0) s_rw[k * 8 + wv] = __popcll(bal);
    }
    if (myfirst != 0x7fffffff) atomicMin(&s_start, myfirst);
    __syncthreads();

    // exclusive scan over 240 (k,wave) counts (pad to 256; waves 0..3)
    {
        int v = 0, inc = 0;
        if (tid < 256) {
            v = (tid < 240) ? s_rw[tid] : 0;
            inc = v;
            #pragma unroll
            for (int d = 1; d < 64; d <<= 1) {
                int o = __shfl_up(inc, d, 64);
                if (lane >= d) inc += o;
            }
            if (lane == 63) s_wt4[wv] = inc;
        }
        __syncthreads();
        if (tid < 256) {
            int off = 0;
            #pragma unroll
            for (int w = 0; w < 4; ++w) off += (w < wv) ? s_wt4[w] : 0;
            s_rw[tid] = off + inc - v;
            if (tid == 255) s_total = off + inc;
        }
        __syncthreads();
    }
    const int Mc = s_total;
    const int start = s_start;
    if (Mc == 0) {
        for (int m = tid; m < MPT; m += FPS_T) fps_idx[b * MPT + m] = 0;
        return;
    }
    const bool use_fallback = (Mc > FPS_CAP);

    // pass 2: order-preserving compaction (compact idx ascending == orig idx
    // ascending) into LDS ptsL (cp mirror only if fallback will run)
    for (int k = 0; k < 30; ++k) {
        bool mm = (mbits >> k) & 1u;
        unsigned long long bal = __ballot(mm);
        int pos = s_rw[k * 8 + wv] + __popcll(bal & ((1ull << lane) - 1ull));
        if (mm) {
            int i = tid + k * FPS_T;
            float x = seed_xyz[(size_t)(b * N_PTS + i) * 3 + 0];
            float y = seed_xyz[(size_t)(b * N_PTS + i) * 3 + 1];
            float z = seed_xyz[(size_t)(b * N_PTS + i) * 3 + 2];
            float4 v4 = make_float4(x, y, z, __int_as_float(i));
            if (use_fallback) cp[cpb + pos] = v4;
            if (pos < FPS_CAP) ptsL[pos] = v4;
            if (i == start) { s_f[0] = x; s_f[1] = y; s_f[2] = z; }
        }
    }
    __threadfence_block();
    __syncthreads();

    if (!use_fallback) {
        // ========== main path: register-resident points, 1 barrier/iter ==========
        float    px[FPS_K], py[FPS_K], pz[FPS_K], pd[FPS_K];
        unsigned plo[FPS_K];                  // ~compact_idx (tie-break key lo)
        #pragma unroll
        for (int k = 0; k < FPS_K; ++k) {
            int c = tid + k * FPS_T;          // c < 8192 always
            bool v = c < Mc;
            float4 t = ptsL[c];
            px[k]  = v ? t.x : 1e9f;
            py[k]  = v ? t.y : 1e9f;
            pz[k]  = v ? t.z : 1e9f;
            pd[k]  = v ? 1e10f : 0.f;
            plo[k] = v ? ~(unsigned)c : 0u;
        }

        // first selection = compact idx 0 = first masked orig index
        float4 f0 = ptsL[0];
        float fx = f0.x, fy = f0.y, fz = f0.z;
        int widx = __float_as_int(f0.w);
        int par = 0;

        #pragma unroll 1
        for (int m = 0; m < MPT; ++m) {
            if (tid == 0) fps_idx[b * MPT + m] = widx;

            uint64_t best = 0;
            #pragma unroll
            for (int k = 0; k < FPS_K; ++k) {
                float dx = __fsub_rn(px[k], fx);
                float dy = __fsub_rn(py[k], fy);
                float dz = __fsub_rn(pz[k], fz);
                float d  = __fadd_rn(__fadd_rn(__fmul_rn(dx, dx), __fmul_rn(dy, dy)),
                                     __fmul_rn(dz, dz));
                float nd = fminf(pd[k], d);
                pd[k] = nd;
                uint64_t cand = ((uint64_t)__float_as_uint(nd) << 32) | plo[k];
                best = cand > best ? cand : best;
            }
            best = dpp_max64_to63(best);
            if (lane == 63) s_pubk[par][wv] = best;
            __syncthreads();
            uint64_t pk = s_pubk[par][lane & 7];
            pk = dpp_max64_to7(pk);
            unsigned glo = (unsigned)__builtin_amdgcn_readlane((int)(unsigned)pk, 7);
            unsigned ci  = ~glo;
            float4 g4 = ptsL[ci];
            fx = g4.x; fy = g4.y; fz = g4.z;
            widx = __float_as_int(g4.w);
            par ^= 1;
        }
    } else {
        // ============ fallback (Mc > 8192): L2 coords, LDS pd ============
        const int L = (Mc + FPS_T - 1) / FPS_T;
        float* pdL = (float*)ptsL;             // Mc <= 15000 -> 60 KB
        for (int c = tid; c < Mc; c += FPS_T) pdL[c] = 1e10f;
        if (lane == 0) {
            s_pub4[0][wv] = make_float4(-1.f, 0.f, 0.f, 0.f);
            s_pub4[1][wv] = make_float4(-1.f, 0.f, 0.f, 0.f);
            s_pubi[0][wv] = 0x7fffffff;
            s_pubi[1][wv] = 0x7fffffff;
        }
        __syncthreads();
        float fx = s_f[0], fy = s_f[1], fz = s_f[2];
        int widx = start;
        int par = 0;
        for (int m = 0; m < MPT; ++m) {
            if (tid == 0) fps_idx[b * MPT + m] = widx;
            float nv = -1.f; int ni = 0x7fffffff;
            float nx = 0.f, ny = 0.f, nz = 0.f;
            for (int k = 0; k < L; ++k) {
                int c = tid * L + k;
                if (c < Mc) {
                    float4 v = cp[cpb + c];
                    float dx = __fsub_rn(v.x, fx);
                    float dy = __fsub_rn(v.y, fy);
                    float dz = __fsub_rn(v.z, fz);
                    float d  = __fadd_rn(__fadd_rn(__fmul_rn(dx, dx), __fmul_rn(dy, dy)),
                                         __fmul_rn(dz, dz));
                    float nd = fminf(pdL[c], d);
                    pdL[c] = nd;
                    int oi = __float_as_int(v.w);
                    bool bt = (nd > nv) || (nd == nv && oi < ni);
                    nv = bt ? nd : nv; ni = bt ? oi : ni;
                    nx = bt ? v.x : nx; ny = bt ? v.y : ny; nz = bt ? v.z : nz;
                }
            }
            unsigned vb = (nv >= 0.f) ? __float_as_uint(nv) : 0u;
            unsigned wmax = (unsigned)__builtin_amdgcn_readlane((int)dpp_max_u32(vb), 63);
            int icand = (vb == wmax) ? ni : 0x7fffffff;
            int wmin = __builtin_amdgcn_readlane(dpp_min_i32(icand), 63);
            if ((vb == wmax) && (ni == wmin) && vb != 0u) {
                s_pub4[par][wv] = make_float4(nv, nx, ny, nz);
                s_pubi[par][wv] = ni;
            }
            __syncthreads();
            {
                float bvv = -2.f; int bii = 0x7fffffff;
                float nfx = 0.f, nfy = 0.f, nfz = 0.f;
                #pragma unroll
                for (int w = 0; w < 8; ++w) {
                    float4 c4 = s_pub4[par][w];
                    int ci2 = s_pubi[par][w];
                    bool bt = (c4.x > bvv) || (c4.x == bvv && ci2 < bii);
                    bvv = bt ? c4.x : bvv; bii = bt ? ci2 : bii;
                    nfx = bt ? c4.y : nfx; nfy = bt ? c4.z : nfy; nfz = bt ? c4.w : nfz;
                }
                fx = nfx; fy = nfy; fz = nfz; widx = bii;
            }
            par ^= 1;
        }
    }
}

// ---------------------------------------------------------------- gathers
__global__ void k_gather(const float* seed_features, const float* seed_xyz,
                         const int* fps_idx, float* feat_g, float* xyz_g)
{
    int e = blockIdx.x;
    if (e < B_SZ * CSEED) {
        int b = e >> 9, c = e & (CSEED - 1);
        const float* src = seed_features + (size_t)(b * CSEED + c) * N_PTS;
        float* dst = feat_g + (size_t)(b * CSEED + c) * MPT;
        const int* idx = fps_idx + b * MPT;
        for (int m = threadIdx.x; m < MPT; m += blockDim.x) dst[m] = src[idx[m]];
    } else {
        int b = e - B_SZ * CSEED;
        const int* idx = fps_idx + b * MPT;
        for (int m = threadIdx.x; m < MPT; m += blockDim.x) {
            int p = idx[m];
            xyz_g[(size_t)(b * MPT + m) * 3 + 0] = seed_xyz[(size_t)(b * N_PTS + p) * 3 + 0];
            xyz_g[(size_t)(b * MPT + m) * 3 + 1] = seed_xyz[(size_t)(b * N_PTS + p) * 3 + 1];
            xyz_g[(size_t)(b * MPT + m) * 3 + 2] = seed_xyz[(size_t)(b * N_PTS + p) * 3 + 2];
        }
    }
}

// ---------------------------------------------------------------- F1T + select fused
// blocks [0,256): F1T = feat_g^T * W1f^T + b1  (p-tile 32 -> fills 256 CUs)
// blocks [256,768): local coords + neighbor select
__global__ __launch_bounds__(256) void k_f1sel(
        const float* feat_g, const float* crop_w1, const float* crop_b1, float* f1t,
        const float* xyz_g, const float* views_rot, int* sel_idx, float* sel_xyz)
{
    __shared__ float A[16][32];
    __shared__ float Bm[16][256];
    __shared__ float s_zloc[4][3];
    __shared__ int   s_padk[4][4];
    __shared__ float s_padx[4][4][3];

    const int tid = threadIdx.x;

    if (blockIdx.x < 256) {
        const int blk = blockIdx.x;
        const int pt = blk & 31;               // 32 p-tiles of 32
        const int b  = (blk >> 5) & 1;
        const int s  = blk >> 6;
        const int p0 = pt * 32;
        const int pg = tid & 7, og = tid >> 3; // p: 8x4, o: 32x8
        float acc[4][8];
        #pragma unroll
        for (int i = 0; i < 4; ++i)
            #pragma unroll
            for (int j = 0; j < 8; ++j) acc[i][j] = 0.f;

        for (int kc = 0; kc < CSEED; kc += 16) {
            __syncthreads();
            {
                int r = tid >> 4, pp = (tid & 15) * 2;
                *(float2*)&A[r][pp] =
                    *(const float2*)&feat_g[(size_t)(b * CSEED + kc + r) * MPT + p0 + pp];
                #pragma unroll
                for (int r2 = 0; r2 < 16; ++r2)
                    Bm[r2][tid] = crop_w1[(size_t)(s * 256 + tid) * 515 + 3 + kc + r2];
            }
            __syncthreads();
            #pragma unroll
            for (int r = 0; r < 16; ++r) {
                float4 a4 = *(const float4*)&A[r][pg * 4];
                float av[4] = {a4.x, a4.y, a4.z, a4.w};
                float bv[8];
                #pragma unroll
                for (int q = 0; q < 2; ++q) {
                    float4 b4 = *(const float4*)&Bm[r][og * 8 + q * 4];
                    bv[q*4+0] = b4.x; bv[q*4+1] = b4.y; bv[q*4+2] = b4.z; bv[q*4+3] = b4.w;
                }
                #pragma unroll
                for (int i = 0; i < 4; ++i)
                    #pragma unroll
                    for (int j = 0; j < 8; ++j)
                        acc[i][j] += av[i] * bv[j];
            }
        }
        #pragma unroll
        for (int i = 0; i < 4; ++i) {
            size_t row = (size_t)((s * B_SZ + b) * MPT + p0 + pg * 4 + i) * 256;
            #pragma unroll
            for (int q = 0; q < 2; ++q) {
                float4 o4;
                o4.x = acc[i][q*4+0] + crop_b1[s*256 + og*8 + q*4+0];
                o4.y = acc[i][q*4+1] + crop_b1[s*256 + og*8 + q*4+1];
                o4.z = acc[i][q*4+2] + crop_b1[s*256 + og*8 + q*4+2];
                o4.w = acc[i][q*4+3] + crop_b1[s*256 + og*8 + q*4+3];
                *(float4*)&f1t[row + og * 8 + q * 4] = o4;
            }
        }
    } else {
        const int wv = tid >> 6;
        const int lane = tid & 63;
        const int gj = (blockIdx.x - 256) * 4 + wv;
        const int b = gj >> 10, j = gj & (MPT - 1);

        const float cx = xyz_g[(size_t)(b * MPT + j) * 3 + 0];
        const float cy = xyz_g[(size_t)(b * MPT + j) * 3 + 1];
        const float cz = xyz_g[(size_t)(b * MPT + j) * 3 + 2];
        const float* R = views_rot + (size_t)(b * MPT + j) * 9;
        const float r00 = R[0], r01 = R[1], r02 = R[2];
        const float r10 = R[3], r11 = R[4], r12 = R[5];
        const float r20 = R[6], r21 = R[7], r22 = R[8];

        const float R2C[4] = { (float)(0.025 * 0.025), (float)(0.0375 * 0.0375),
                               (float)(0.05 * 0.05),   (float)(0.075 * 0.075) };
        const int NSs[4] = {16, 32, 32, 64};

        int cnt[4] = {0, 0, 0, 0};

        for (int ch = 0; ch < 16; ++ch) {
            int k = ch * 64 + lane;
            float x = xyz_g[(size_t)(b * MPT + k) * 3 + 0];
            float y = xyz_g[(size_t)(b * MPT + k) * 3 + 1];
            float z = xyz_g[(size_t)(b * MPT + k) * 3 + 2];
            float rx = __fsub_rn(x, cx), ry = __fsub_rn(y, cy), rz = __fsub_rn(z, cz);
            float l0 = __fadd_rn(__fadd_rn(__fmul_rn(rx, r00), __fmul_rn(ry, r10)), __fmul_rn(rz, r20));
            float l1 = __fadd_rn(__fadd_rn(__fmul_rn(rx, r01), __fmul_rn(ry, r11)), __fmul_rn(rz, r21));
            float l2 = __fadd_rn(__fadd_rn(__fmul_rn(rx, r02), __fmul_rn(ry, r12)), __fmul_rn(rz, r22));
            float r2 = __fadd_rn(__fmul_rn(l1, l1), __fmul_rn(l2, l2));
            bool inh = (l0 >= HMINF) && (l0 <= HMAXF);
            if (ch == 0 && lane == 0) { s_zloc[wv][0] = l0; s_zloc[wv][1] = l1; s_zloc[wv][2] = l2; }
            #pragma unroll
            for (int sc = 0; sc < 4; ++sc) {
                bool v = inh && (r2 < R2C[sc]);
                unsigned long long bal = __ballot(v);
                int pre = __popcll(bal & ((1ull << lane) - 1ull));
                int p = cnt[sc] + pre;
                if (v && p < NSs[sc]) {
                    size_t sb = ((size_t)(sc * B_SZ + b) * MPT + j) * 64 + p;
                    sel_idx[sb] = k;
                    sel_xyz[sb * 3 + 0] = l0;
                    sel_xyz[sb * 3 + 1] = l1;
                    sel_xyz[sb * 3 + 2] = l2;
                    if (p == 0) {
                        s_padk[wv][sc] = k;
                        s_padx[wv][sc][0] = l0; s_padx[wv][sc][1] = l1; s_padx[wv][sc][2] = l2;
                    }
                }
                cnt[sc] += __popcll(bal);
            }
        }
        __syncthreads();
        #pragma unroll
        for (int sc = 0; sc < 4; ++sc) {
            int cs = cnt[sc];
            int pk; float a0, a1, a2;
            if (cs > 0) { pk = s_padk[wv][sc]; a0 = s_padx[wv][sc][0]; a1 = s_padx[wv][sc][1]; a2 = s_padx[wv][sc][2]; }
            else        { pk = 0; a0 = s_zloc[wv][0]; a1 = s_zloc[wv][1]; a2 = s_zloc[wv][2]; }
            for (int n = cs + lane; n < NSs[sc]; n += 64) {
                size_t sb = ((size_t)(sc * B_SZ + b) * MPT + j) * 64 + n;
                sel_idx[sb] = pk;
                sel_xyz[sb * 3 + 0] = a0; sel_xyz[sb * 3 + 1] = a1; sel_xyz[sb * 3 + 2] = a2;
            }
        }
    }
}

// ---------------------------------------------------------------- crop MLP via bf16 MFMA
// wave wv owns o-tiles [8wv, 8wv+8) over ALL 64 h1 cols; W2 read once/block.
__global__ __launch_bounds__(256) void k_crop(
        const float* f1t, const float* crop_w1, const unsigned short* w2bf,
        const float* crop_b2, const int* sel_idx, const float* sel_xyz, float* vp_cat)
{
    const int blk0 = blockIdx.x;
    int s, log2ns, base;
    if (blk0 < 512)       { s = 0; log2ns = 4; base = 0; }
    else if (blk0 < 1536) { s = 1; log2ns = 5; base = 512; }
    else if (blk0 < 2560) { s = 2; log2ns = 5; base = 1536; }
    else                  { s = 3; log2ns = 6; base = 2560; }
    const int ns = 1 << log2ns;
    const int rel = blk0 - base;

    const int tid = threadIdx.x;
    const int jt = 64 >> log2ns;
    const int nj = MPT / jt;
    const int b = rel / nj;
    const int jbase = (rel % nj) * jt;

    __shared__ unsigned short h1T[64 * 264];   // [col][c] bf16, stride 264
    __shared__ float w1xa[3 * 256];

    for (int i = tid; i < 768; i += 256) {
        int a = i >> 8, o = i & 255;
        w1xa[i] = crop_w1[(size_t)(s * 256 + o) * 515 + a];
    }
    __syncthreads();

    // phase 1: h1 = relu(f1row + W1x*xyz) -> bf16 -> h1T
    {
        const int col = tid & 63;
        const int cq = tid >> 6;
        const int jl = col >> log2ns;
        const int nn = col & (ns - 1);
        const size_t sb = ((size_t)(s * B_SZ + b) * MPT + jbase + jl) * 64 + nn;
        const int p = sel_idx[sb];
        const float gx = sel_xyz[sb * 3 + 0];
        const float gy = sel_xyz[sb * 3 + 1];
        const float gz = sel_xyz[sb * 3 + 2];
        const float* f1row = f1t + (size_t)((s * B_SZ + b) * MPT + p) * 256;
        #pragma unroll
        for (int c4 = 0; c4 < 16; ++c4) {
            int c0 = cq * 64 + c4 * 4;
            float4 fv = *(const float4*)&f1row[c0];
            float v0 = fmaxf(fv.x + w1xa[c0+0]*gx + w1xa[256+c0+0]*gy + w1xa[512+c0+0]*gz, 0.f);
            float v1 = fmaxf(fv.y + w1xa[c0+1]*gx + w1xa[256+c0+1]*gy + w1xa[512+c0+1]*gz, 0.f);
            float v2 = fmaxf(fv.z + w1xa[c0+2]*gx + w1xa[256+c0+2]*gy + w1xa[512+c0+2]*gz, 0.f);
            float v3 = fmaxf(fv.w + w1xa[c0+3]*gx + w1xa[256+c0+3]*gy + w1xa[512+c0+3]*gz, 0.f);
            unsigned lo = (unsigned)f2bf(v0) | ((unsigned)f2bf(v1) << 16);
            unsigned hi = (unsigned)f2bf(v2) | ((unsigned)f2bf(v3) << 16);
            *(uint2*)&h1T[col * 264 + c0] = make_uint2(lo, hi);
        }
    }
    __syncthreads();

    // phase 2: wave wv -> o-tiles [8wv, 8wv+8), all 64 cols via 4 A-groups
    {
        const int wv = tid >> 6;
        const int lane = tid & 63;
        const int lm = lane & 15, lq = lane >> 4;
        const unsigned short* wbase = w2bf + (size_t)s * 512 * 256;

        #pragma unroll 1
        for (int t = 0; t < 8; ++t) {
            const int ot = wv * 8 + t;
            bf16x8 bb[8];
            #pragma unroll
            for (int kk = 0; kk < 8; ++kk)
                bb[kk] = *(const bf16x8*)&wbase[(size_t)(ot * 16 + lm) * 256 + kk * 32 + lq * 8];

            float mg[4];
            #pragma unroll
            for (int g = 0; g < 4; ++g) {
                f32x4 acc = {0.f, 0.f, 0.f, 0.f};
                #pragma unroll
                for (int kk = 0; kk < 8; ++kk) {
                    bf16x8 af = *(const bf16x8*)&h1T[(g * 16 + lm) * 264 + kk * 32 + lq * 8];
                    acc = __builtin_amdgcn_mfma_f32_16x16x32_bf16(af, bb[kk], acc, 0, 0, 0);
                }
                mg[g] = fmaxf(fmaxf(acc[0], acc[1]), fmaxf(acc[2], acc[3]));
            }

            if (log2ns == 4) {                 // jt=4: group == center
                #pragma unroll
                for (int g = 0; g < 4; ++g) {
                    float v = mg[g];
                    v = fmaxf(v, __shfl_xor(v, 16, 64));
                    v = fmaxf(v, __shfl_xor(v, 32, 64));
                    mg[g] = v;
                }
                if (lane < 16) {
                    int o = ot * 16 + lane;
                    float b2v = crop_b2[s * 512 + o];
                    size_t rowb = ((size_t)(b * 4 + s) * 512 + o) * MPT + jbase;
                    vp_cat[rowb + 0] = fmaxf(mg[0] + b2v, 0.f);
                    vp_cat[rowb + 1] = fmaxf(mg[1] + b2v, 0.f);
                    vp_cat[rowb + 2] = fmaxf(mg[2] + b2v, 0.f);
                    vp_cat[rowb + 3] = fmaxf(mg[3] + b2v, 0.f);
                }
            } else if (log2ns == 5) {          // jt=2: centers = group pairs
                float c0 = fmaxf(mg[0], mg[1]);
                float c1 = fmaxf(mg[2], mg[3]);
                c0 = fmaxf(c0, __shfl_xor(c0, 16, 64));
                c0 = fmaxf(c0, __shfl_xor(c0, 32, 64));
                c1 = fmaxf(c1, __shfl_xor(c1, 16, 64));
                c1 = fmaxf(c1, __shfl_xor(c1, 32, 64));
                if (lane < 16) {
                    int o = ot * 16 + lane;
                    float b2v = crop_b2[s * 512 + o];
                    size_t rowb = ((size_t)(b * 4 + s) * 512 + o) * MPT + jbase;
                    vp_cat[rowb + 0] = fmaxf(c0 + b2v, 0.f);
                    vp_cat[rowb + 1] = fmaxf(c1 + b2v, 0.f);
                }
            } else {                           // jt=1: one center, all groups
                float c0 = fmaxf(fmaxf(mg[0], mg[1]), fmaxf(mg[2], mg[3]));
                c0 = fmaxf(c0, __shfl_xor(c0, 16, 64));
                c0 = fmaxf(c0, __shfl_xor(c0, 32, 64));
                if (lane < 16) {
                    int o = ot * 16 + lane;
                    vp_cat[((size_t)(b * 4 + s) * 512 + o) * MPT + jbase] =
                        fmaxf(c0 + crop_b2[s * 512 + o], 0.f);
                }
            }
        }
    }
}

// ---------------------------------------------------------------- fuse + gate + output
// 512 blocks (o-tile 64 x m-tile 32), 2 blocks/CU. K-chunk 32.
__global__ __launch_bounds__(256, 2) void k_out(
        const float* vp_cat, const float* feat_g,
        const float* fuse_w, const float* fuse_b,
        const float* gate_w, const float* gate_b, float* out)
{
    const int blk = blockIdx.x;
    const int mt = blk & 31;                   // 32 m-tiles of 32
    const int ot = (blk >> 5) & 7;             // 8 o-tiles of 64
    const int b  = blk >> 8;
    const int o0b = ot * 64, m0b = mt * 32;
    __shared__ float A[32 * 64];               // 8 KB
    __shared__ float Bm[32 * 32];              // 4 KB
    const int tid = threadIdx.x;
    const int og = tid >> 3;                   // 32 groups x 2 o
    const int mg = tid & 7;                    // 8 groups x 4 m
    float acc1[2][4], acc2[2][4];
    #pragma unroll
    for (int i = 0; i < 2; ++i)
        #pragma unroll
        for (int jq = 0; jq < 4; ++jq) { acc1[i][jq] = 0.f; acc2[i][jq] = 0.f; }

    for (int kc = 0; kc < 2048; kc += 32) {
        __syncthreads();
        {
            int oo = tid & 63, r8 = (tid >> 6) * 8;
            const float* srow = &fuse_w[(size_t)(o0b + oo) * 2048 + kc + r8];
            float4 u0 = *(const float4*)srow;
            float4 u1 = *(const float4*)(srow + 4);
            A[(r8 + 0) * 64 + oo] = u0.x; A[(r8 + 1) * 64 + oo] = u0.y;
            A[(r8 + 2) * 64 + oo] = u0.z; A[(r8 + 3) * 64 + oo] = u0.w;
            A[(r8 + 4) * 64 + oo] = u1.x; A[(r8 + 5) * 64 + oo] = u1.y;
            A[(r8 + 6) * 64 + oo] = u1.z; A[(r8 + 7) * 64 + oo] = u1.w;
            int r = tid >> 3, mm = (tid & 7) * 4;
            *(float4*)&Bm[r * 32 + mm] =
                *(const float4*)&vp_cat[((size_t)b * 2048 + kc + r) * MPT + m0b + mm];
        }
        __syncthreads();
        #pragma unroll
        for (int r = 0; r < 32; ++r) {
            float2 a0 = *(const float2*)&A[r * 64 + og * 2];
            float4 bb = *(const float4*)&Bm[r * 32 + mg * 4];
            float av[2] = {a0.x, a0.y};
            float bv[4] = {bb.x, bb.y, bb.z, bb.w};
            #pragma unroll
            for (int oi = 0; oi < 2; ++oi)
                #pragma unroll
                for (int mi = 0; mi < 4; ++mi)
                    acc1[oi][mi] += av[oi] * bv[mi];
        }
    }
    for (int kc = 0; kc < 512; kc += 32) {
        __syncthreads();
        {
            int oo = tid & 63, r8 = (tid >> 6) * 8;
            const float* srow = &gate_w[(size_t)(o0b + oo) * 512 + kc + r8];
            float4 u0 = *(const float4*)srow;
            float4 u1 = *(const float4*)(srow + 4);
            A[(r8 + 0) * 64 + oo] = u0.x; A[(r8 + 1) * 64 + oo] = u0.y;
            A[(r8 + 2) * 64 + oo] = u0.z; A[(r8 + 3) * 64 + oo] = u0.w;
            A[(r8 + 4) * 64 + oo] = u1.x; A[(r8 + 5) * 64 + oo] = u1.y;
            A[(r8 + 6) * 64 + oo] = u1.z; A[(r8 + 7) * 64 + oo] = u1.w;
            int r = tid >> 3, mm = (tid & 7) * 4;
            *(float4*)&Bm[r * 32 + mm] =
                *(const float4*)&feat_g[((size_t)b * CSEED + kc + r) * MPT + m0b + mm];
        }
        __syncthreads();
        #pragma unroll
        for (int r = 0; r < 32; ++r) {
            float2 a0 = *(const float2*)&A[r * 64 + og * 2];
            float4 bb = *(const float4*)&Bm[r * 32 + mg * 4];
            float av[2] = {a0.x, a0.y};
            float bv[4] = {bb.x, bb.y, bb.z, bb.w};
            #pragma unroll
            for (int oi = 0; oi < 2; ++oi)
                #pragma unroll
                for (int mi = 0; mi < 4; ++mi)
                    acc2[oi][mi] += av[oi] * bv[mi];
        }
    }
    #pragma unroll
    for (int oi = 0; oi < 2; ++oi) {
        int o = o0b + og * 2 + oi;
        float fb = fuse_b[o], gb = gate_b[o];
        #pragma unroll
        for (int mi = 0; mi < 4; ++mi) {
            int m = m0b + mg * 4 + mi;
            float f = acc1[oi][mi] + fb;
            float gl = acc2[oi][mi] + gb;
            float gt = 1.f / (1.f + __expf(-gl));
            float fg = feat_g[((size_t)b * CSEED + o) * MPT + m];
            out[((size_t)b * CSEED + o) * MPT + m] = f + gt * fg;
        }
    }
}

// ---------------------------------------------------------------- launcher
extern "C" void kernel_launch(void* const* d_in, const int* in_sizes, int n_in,
                              void* d_out, int out_size, void* d_ws, size_t ws_size,
                              hipStream_t stream) {
    const float* seed_xyz      = (const float*)d_in[0];
    const float* seed_features = (const float*)d_in[1];
    const void*  mask_raw      = d_in[2];
    const float* views_rot     = (const float*)d_in[3];
    const float* crop_w1       = (const float*)d_in[4];
    const float* crop_b1       = (const float*)d_in[5];
    const float* crop_w2       = (const float*)d_in[6];
    const float* crop_b2       = (const float*)d_in[7];
    const float* fuse_w        = (const float*)d_in[8];
    const float* fuse_b        = (const float*)d_in[9];
    const float* gate_w        = (const float*)d_in[10];
    const float* gate_b        = (const float*)d_in[11];
    float* out = (float*)d_out;

    char* ws = (char*)d_ws;
    size_t off = 0;
    auto alloc = [&](size_t bytes) -> void* {
        void* p = ws + off;
        off = (off + bytes + 255) & ~(size_t)255;
        return p;
    };
    int*            fpsidx = (int*)            alloc((size_t)B_SZ * MPT * 4);
    float4*         cp     = (float4*)         alloc((size_t)B_SZ * 15008 * 16);
    float*          xyzg   = (float*)          alloc((size_t)B_SZ * MPT * 3 * 4);
    float*          featg  = (float*)          alloc((size_t)B_SZ * CSEED * MPT * 4);
    float*          f1t    = (float*)          alloc((size_t)4 * B_SZ * MPT * 256 * 4);
    int*            selidx = (int*)            alloc((size_t)4 * B_SZ * MPT * 64 * 4);
    float*          selxyz = (float*)          alloc((size_t)4 * B_SZ * MPT * 64 * 3 * 4);
    unsigned short* w2bf   = (unsigned short*) alloc((size_t)4 * 512 * 256 * 2);
    float*          vpcat  = (float*)          alloc((size_t)B_SZ * 4 * 512 * MPT * 4);

    k_fps<<<B_SZ + W2_BLKS, FPS_T, 0, stream>>>(mask_raw, seed_xyz, cp, fpsidx, crop_w2, w2bf);
    k_gather<<<B_SZ * CSEED + B_SZ, 256, 0, stream>>>(
        seed_features, seed_xyz, fpsidx, featg, xyzg);
    k_f1sel<<<256 + (B_SZ * MPT) / 4, 256, 0, stream>>>(
        featg, crop_w1, crop_b1, f1t, xyzg, views_rot, selidx, selxyz);
    k_crop<<<4608, 256, 0, stream>>>(f1t, crop_w1, w2bf, crop_b2, selidx, selxyz, vpcat);
    k_out<<<512, 256, 0, stream>>>(vpcat, featg, fuse_w, fuse_b, gate_w, gate_b, out);
}